// Round 1
// 3138.421 us; speedup vs baseline: 2.0889x; 2.0889x over previous
//
#include <hip/hip_runtime.h>

// CosformerAttention: L=4096, B=4, E=1024, H=16, HD=64, n=B*H=64 heads.
// Round 8: replace scalar k_kv_s (3.57ms, per-element sinf/cosf, no tiling)
// with LDS-tiled register-blocked batched GEMM k_kv2 (~100us predicted).
//  k_proj_s: unchanged scalar LDS-tiled f32 GEMM. Q (f32) -> d_out, K,V (bf16) -> ws.
//  k_kv2   : kv[head][d][m] = sum_l feat_d(l)*relu_k(l,d&63)*v_ext(l,m)
//            64 heads x 8 L-chunks, 32-row LDS tiles, 4x8 acc patch/thread,
//            cross-chunk reduce via device-scope atomicAdd (kv zeroed by memset).
//  k_attn_s: unchanged. out = (q_ . kv) / max(q_ . ksum, eps), f32 in/out.

typedef unsigned short ushortt;
typedef unsigned int u32;

#define L_DIM 4096
#define B_DIM 4
#define E_DIM 1024

#define KV_CH 8                    // L chunks for k_kv2
#define KV_LCH (L_DIM / KV_CH)     // 512 rows per chunk
#define KV_LT 32                   // l-tile rows staged in LDS

__device__ __forceinline__ ushortt f2bf(float f) {
    union { float f; u32 u; } v; v.f = f;
    u32 u = v.u;
    u += 0x7FFFu + ((u >> 16) & 1u);   // round-to-nearest-even
    return (ushortt)(u >> 16);
}
__device__ __forceinline__ float bf2f(ushortt h) {
    union { u32 u; float f; } v; v.u = ((u32)h) << 16;
    return v.f;
}

// ---------------- Kernel 1 (scalar): projection GEMM --------------------------
// Y[m][n] = relu?(sum_k X[m][k] * W[n][k] + b[n]),  m = l*B+b (16384), n (1024).
// grid: x = 256 (M/64), y = 48 (proj*16 + ntile). block 256 = 16x16 threads,
// each thread computes a 4x4 output patch. Pure f32 scalar FMA from LDS.
// p==0 (Q): store f32 into Qf (= d_out). p==1,2 (K,V): store bf16 into ws.
__global__ __launch_bounds__(256) void k_proj_s(
    const float* __restrict__ xq, const float* __restrict__ xk, const float* __restrict__ xv,
    const float* __restrict__ wq, const float* __restrict__ bq,
    const float* __restrict__ wk, const float* __restrict__ bk,
    const float* __restrict__ wv, const float* __restrict__ bv,
    float* __restrict__ Qf, ushortt* __restrict__ Kb, ushortt* __restrict__ Vb)
{
    __shared__ float sX[64 * 33];   // 64 rows x 32 k, +1 pad
    __shared__ float sW[64 * 33];

    const int t = threadIdx.x;
    const int tx = t & 15, ty = t >> 4;

    const int p = blockIdx.y >> 4;             // 0=q, 1=k, 2=v
    const int nblk = (blockIdx.y & 15) * 64;   // output col base
    const int mblk = blockIdx.x * 64;          // output row base

    const float* X = (p == 0) ? xq : (p == 1) ? xk : xv;
    const float* W = (p == 0) ? wq : (p == 1) ? wk : wv;
    const float* bias = (p == 0) ? bq : (p == 1) ? bk : bv;
    const bool do_relu = (p < 2);

    float acc[4][4];
#pragma unroll
    for (int i = 0; i < 4; i++)
#pragma unroll
        for (int j = 0; j < 4; j++) acc[i][j] = 0.0f;

    for (int k0 = 0; k0 < 1024; k0 += 32) {
        __syncthreads();   // previous tile fully consumed
#pragma unroll
        for (int i = 0; i < 8; i++) {
            const int idx = t + 256 * i;       // 0..2047
            const int r = idx >> 5, c = idx & 31;
            sX[r * 33 + c] = X[(size_t)(mblk + r) * E_DIM + k0 + c];
            sW[r * 33 + c] = W[(size_t)(nblk + r) * E_DIM + k0 + c];
        }
        __syncthreads();
#pragma unroll 4
        for (int kk = 0; kk < 32; kk++) {
            float a[4], w[4];
#pragma unroll
            for (int i = 0; i < 4; i++) a[i] = sX[(ty * 4 + i) * 33 + kk];
#pragma unroll
            for (int j = 0; j < 4; j++) w[j] = sW[(tx * 4 + j) * 33 + kk];
#pragma unroll
            for (int i = 0; i < 4; i++)
#pragma unroll
                for (int j = 0; j < 4; j++) acc[i][j] += a[i] * w[j];
        }
    }

#pragma unroll
    for (int j = 0; j < 4; j++) {
        const int col = nblk + tx * 4 + j;
        const float bj = bias[col];
#pragma unroll
        for (int i = 0; i < 4; i++) {
            const int row = mblk + ty * 4 + i;
            float v = acc[i][j] + bj;
            if (do_relu) v = fmaxf(v, 0.0f);
            if (p == 0)      Qf[(size_t)row * E_DIM + col] = v;        // f32
            else if (p == 1) Kb[(size_t)row * E_DIM + col] = f2bf(v);  // bf16
            else             Vb[(size_t)row * E_DIM + col] = f2bf(v);  // bf16
        }
    }
}

// ---------------- Kernel 2: kv[head][d][m] batched tiled GEMM ----------------
// kv[head][d][m] = sum_l sk[l][d] * vext[l][m]
//   sk[l][d]   = (d<64 ? sin(ang_l) : cos(ang_l)) * relu_k[l][d&63]
//   vext[l][m] = v[l][m] (m<64), 1.0 (m==64 -> ksum column)
// grid: x = 64 heads, y = KV_CH L-chunks. block 256.
// Thread t owns d in [dq*4, dq*4+4) x m in [mq*8, mq*8+8), dq=t>>3, mq=t&7.
// Per l: 1 float4 from sk (conflict-free) + 2 float4 from sv (2-way, free)
// feeding 32 FMAs. Cross-chunk reduction: device-scope atomicAdd (kv pre-zeroed).
__global__ __launch_bounds__(256) void k_kv2(
    const ushortt* __restrict__ Kb, const ushortt* __restrict__ Vb,
    float* __restrict__ kv)
{
    __shared__ float sk[KV_LT][128];   // feature-mapped K tile
    __shared__ float sv[KV_LT][64];    // V tile

    const int head = blockIdx.x;
    const int b = head >> 4, hh = head & 15;
    const int t = threadIdx.x;
    const int mq = t & 7;              // m base = mq*8
    const int dq = t >> 3;             // d base = dq*4
    const int l0base = blockIdx.y * KV_LCH;

    float acc[4][8];
    float ksum[4];
#pragma unroll
    for (int i = 0; i < 4; i++) {
        ksum[i] = 0.0f;
#pragma unroll
        for (int j = 0; j < 8; j++) acc[i][j] = 0.0f;
    }

    const size_t headoff = (size_t)hh * 64;

    for (int l0 = l0base; l0 < l0base + KV_LCH; l0 += KV_LT) {
        __syncthreads();   // previous tile fully consumed
        // Stage: KV_LT*64 bf16 each of K and V, 4 elems (8B) per load.
#pragma unroll
        for (int i = 0; i < 2; i++) {
            const int j = t + 256 * i;         // 0..511
            const int l = j >> 4;              // 0..31
            const int c4 = (j & 15) << 2;      // 0,4,...,60
            const size_t rowb = ((size_t)(l0 + l) * B_DIM + b) * E_DIM + headoff;
            const uint2 kraw = *reinterpret_cast<const uint2*>(Kb + rowb + c4);
            const uint2 vraw = *reinterpret_cast<const uint2*>(Vb + rowb + c4);
            const float ang = 1.5707963267948966f * (float)(l0 + l + 1) * (1.0f / 4096.0f);
            const float sn = sinf(ang), cs = cosf(ang);
            const float k0 = bf2f((ushortt)(kraw.x & 0xffffu));
            const float k1 = bf2f((ushortt)(kraw.x >> 16));
            const float k2 = bf2f((ushortt)(kraw.y & 0xffffu));
            const float k3 = bf2f((ushortt)(kraw.y >> 16));
            *reinterpret_cast<float4*>(&sk[l][c4]) =
                make_float4(sn * k0, sn * k1, sn * k2, sn * k3);
            *reinterpret_cast<float4*>(&sk[l][64 + c4]) =
                make_float4(cs * k0, cs * k1, cs * k2, cs * k3);
            *reinterpret_cast<float4*>(&sv[l][c4]) =
                make_float4(bf2f((ushortt)(vraw.x & 0xffffu)),
                            bf2f((ushortt)(vraw.x >> 16)),
                            bf2f((ushortt)(vraw.y & 0xffffu)),
                            bf2f((ushortt)(vraw.y >> 16)));
        }
        __syncthreads();
#pragma unroll 8
        for (int l = 0; l < KV_LT; l++) {
            const float4 a4 = *reinterpret_cast<const float4*>(&sk[l][dq << 2]);
            const float4 v0 = *reinterpret_cast<const float4*>(&sv[l][mq << 3]);
            const float4 v1 = *reinterpret_cast<const float4*>(&sv[l][(mq << 3) + 4]);
            const float av[4] = { a4.x, a4.y, a4.z, a4.w };
            const float vv[8] = { v0.x, v0.y, v0.z, v0.w, v1.x, v1.y, v1.z, v1.w };
#pragma unroll
            for (int i = 0; i < 4; i++) {
#pragma unroll
                for (int j = 0; j < 8; j++) acc[i][j] += av[i] * vv[j];
                ksum[i] += av[i];
            }
        }
    }

    float* dst = kv + (size_t)head * (128 * 65);
    const int d0 = dq << 2, m0 = mq << 3;
#pragma unroll
    for (int i = 0; i < 4; i++) {
#pragma unroll
        for (int j = 0; j < 8; j++)
            atomicAdd(&dst[(d0 + i) * 65 + m0 + j], acc[i][j]);
        if (mq == 0)
            atomicAdd(&dst[(d0 + i) * 65 + 64], ksum[i]);
    }
}

// ---------------- Kernel 3 (scalar): out = (q_ . kv) / max(q_ . ksum, eps) ---
// grid: 65536 blocks x 256 threads = one thread per output element. f32 I/O.
// qout aliasing: block stages its OWN 256 q elements into LDS, barrier, then
// computes and overwrites exactly those elements. No cross-block sharing.
__global__ __launch_bounds__(256) void k_attn_s(
    float* qout, const float* __restrict__ kv)
{
    __shared__ float qs[256];
    const int t = threadIdx.x;
    const size_t idx = (size_t)blockIdx.x * 256 + t;
    const int l = (int)(idx >> 12);          // B*E = 4096
    const int rem = (int)(idx & 4095);
    const int b = rem >> 10;
    const int e = rem & 1023;
    const int hh = e >> 6;
    const int m = e & 63;
    const int head = b * 16 + hh;

    qs[t] = qout[idx];                       // relu'd q (f32) from k_proj_s
    __syncthreads();

    const float ang = 1.5707963267948966f * (float)(l + 1) * (1.0f / 4096.0f);
    const float s = sinf(ang), c = cosf(ang);
    const float* kvh = kv + (size_t)head * 128 * 65;
    const int qbase = t & 192;               // head-slice base within block

    float numer = 0.0f, den = 0.0f;
#pragma unroll 8
    for (int dd = 0; dd < 64; ++dd) {
        const float qv = qs[qbase + dd];
        numer += qv * (s * kvh[dd * 65 + m] + c * kvh[(dd + 64) * 65 + m]);
        den   += qv * (s * kvh[dd * 65 + 64] + c * kvh[(dd + 64) * 65 + 64]);
    }
    const float z = 1.0f / fmaxf(den, 1e-4f);
    qout[idx] = numer * z;                   // f32 output
}

extern "C" void kernel_launch(void* const* d_in, const int* in_sizes, int n_in,
                              void* d_out, int out_size, void* d_ws, size_t ws_size,
                              hipStream_t stream) {
    (void)in_sizes; (void)n_in; (void)out_size; (void)ws_size;
    const float* xq = (const float*)d_in[0];
    const float* xk = (const float*)d_in[1];
    const float* xv = (const float*)d_in[2];
    const float* wq = (const float*)d_in[3];
    const float* bq = (const float*)d_in[4];
    const float* wk = (const float*)d_in[5];
    const float* bk = (const float*)d_in[6];
    const float* wv = (const float*)d_in[7];
    const float* bv = (const float*)d_in[8];
    float* out = (float*)d_out;  // f32; doubles as Q-projection scratch

    char* ws = (char*)d_ws;
    // ws layout (bytes): Kb 33.55MB | Vb 33.55MB | kv 2.13MB => ~69.2MB
    ushortt* Kb = (ushortt*)(ws);
    ushortt* Vb = (ushortt*)(ws + 33554432);
    float* kv = (float*)(ws + 67108864);

    dim3 blk(256);
    k_proj_s<<<dim3(256, 48), blk, 0, stream>>>(xq, xk, xv, wq, bq, wk, bk, wv, bv, out, Kb, Vb);
    hipMemsetAsync(kv, 0, (size_t)64 * 128 * 65 * sizeof(float), stream);
    k_kv2<<<dim3(64, KV_CH), blk, 0, stream>>>(Kb, Vb, kv);
    k_attn_s<<<dim3(65536), blk, 0, stream>>>(out, kv);
}

// Round 2
// 1125.358 us; speedup vs baseline: 5.8255x; 2.7888x over previous
//
#include <hip/hip_runtime.h>
#include <hip/hip_bf16.h>

// CosformerAttention: L=4096, B=4, E=1024, H=16, HD=64, n=B*H=64 heads.
// Round 9: MFMA projection GEMM (was scalar VALU, 2.6ms, 3e8 bank conflicts).
//  k_cvtW : W f32 -> bf16 (RNE), 2MB buffer aliasing kv region (time-disjoint).
//  k_gemm : 128x128xBK32 bf16 MFMA, 4 waves, global_load_lds staging with
//           pre-swizzled global sources (XOR bank swizzle, linear LDS dest),
//           A kept f32 in LDS, converted to bf16 frags in-register.
//           XCD-aware bijective block swizzle (1024 blocks).
//  k_kv2  : unchanged (LDS-tiled batched GEMM + atomic reduce).
//  k_attn_s: unchanged.

typedef unsigned short ushortt;
typedef unsigned int u32;
typedef __attribute__((ext_vector_type(8))) short bf16x8;
typedef __attribute__((ext_vector_type(4))) float f32x4;

#define L_DIM 4096
#define B_DIM 4
#define E_DIM 1024

#define KV_CH 8                    // L chunks for k_kv2
#define KV_LCH (L_DIM / KV_CH)     // 512 rows per chunk
#define KV_LT 32                   // l-tile rows staged in LDS

__device__ __forceinline__ ushortt f2bf(float f) {
    union { float f; u32 u; } v; v.f = f;
    u32 u = v.u;
    u += 0x7FFFu + ((u >> 16) & 1u);   // round-to-nearest-even
    return (ushortt)(u >> 16);
}
__device__ __forceinline__ float bf2f(ushortt h) {
    union { u32 u; float f; } v; v.u = ((u32)h) << 16;
    return v.f;
}

__device__ __forceinline__ void gl_lds16(const void* g, void* l) {
    __builtin_amdgcn_global_load_lds(
        (const __attribute__((address_space(1))) unsigned int*)g,
        (__attribute__((address_space(3))) unsigned int*)l, 16, 0, 0);
}

// pack 8 f32 -> 8 bf16 (RNE via hw cvt_pk)
__device__ __forceinline__ bf16x8 cvt8(float4 a, float4 b) {
    union { bf16x8 v; __hip_bfloat162 h[4]; } r;
    r.h[0] = __float22bfloat162_rn(make_float2(a.x, a.y));
    r.h[1] = __float22bfloat162_rn(make_float2(a.z, a.w));
    r.h[2] = __float22bfloat162_rn(make_float2(b.x, b.y));
    r.h[3] = __float22bfloat162_rn(make_float2(b.z, b.w));
    return r.v;
}

// ---------------- W f32 -> bf16 converter ------------------------------------
__global__ __launch_bounds__(256) void k_cvtW(
    const float* __restrict__ W, ushortt* __restrict__ Wb)
{
    const int i = (blockIdx.x * 256 + threadIdx.x) * 4;   // 1M elems
    const float4 v = *reinterpret_cast<const float4*>(W + i);
    ushortt o[4] = { f2bf(v.x), f2bf(v.y), f2bf(v.z), f2bf(v.w) };
    *reinterpret_cast<uint2*>(Wb + i) = *reinterpret_cast<uint2*>(o);
}

// ---------------- MFMA projection GEMM ---------------------------------------
// Y[m][n] = relu?(sum_k X[m][k]*W[n][k] + b[n]); M=16384, N=1024, K=1024.
// Tile 128x128, BK=32. 4 waves (2x2), each wave 64x64 via 4x4 of 16x16x32 MFMA.
// sA: [128 rows][32 f32] rows 128B, XOR-swizzled by ((row&7)<<4) on 16B slots.
// sB: [128 rows][32 bf16] rows 64B, XOR-swizzled by (((row>>1)&3)<<4).
// Swizzle realized by permuting the *global source* of global_load_lds (linear
// LDS dest), and applying the same XOR on the ds_read side. All frag reads are
// 2-way bank aliased (free).
__global__ __launch_bounds__(256) void k_gemm(
    const float* __restrict__ X, const ushortt* __restrict__ Wb,
    const float* __restrict__ bias,
    float* __restrict__ Of, ushortt* __restrict__ Ob, const int p)
{
    __shared__ char sA[16384];     // 128 x 128B
    __shared__ char sB[8192];      // 128 x 64B

    const int t = threadIdx.x;
    const int ln = t & 63;
    const int wv = t >> 6;
    const int wr = wv >> 1, wc = wv & 1;

    // XCD-aware bijective swizzle: 1024 blocks, xcd = orig%8 gets 128 contiguous.
    const int orig = blockIdx.x;
    const int bid = (orig & 7) * 128 + (orig >> 3);
    const int mblk = (bid >> 3) * 128;
    const int nblk = (bid & 7) * 128;

    f32x4 acc[4][4];
#pragma unroll
    for (int i = 0; i < 4; i++)
#pragma unroll
        for (int j = 0; j < 4; j++) acc[i][j] = (f32x4){0.f, 0.f, 0.f, 0.f};

    // staging lane constants
    const int aRowIn = ln >> 3;                               // row within 8-row chunk
    const int aSrcE  = ((ln & 7) ^ aRowIn) << 2;              // f32 elems (pre-swizzled)
    const int bRowIn = ln >> 2;                               // row within 16-row chunk
    const int bSrcE  = (((ln & 3) ^ ((ln >> 3) & 3))) << 3;   // bf16 elems (pre-swizzled)

    // frag-read lane constants
    const int g   = ln >> 4;
    const int r15 = ln & 15;
    const int swA = (ln & 7) << 4;          // = ((row&7)<<4), row = ...+(ln&15)
    const int swB = ((ln >> 1) & 3) << 4;   // = (((n>>1)&3)<<4)

    for (int k0 = 0; k0 < 1024; k0 += 32) {
        __syncthreads();
        // ---- stage A: 16 chunks x 1KB (8 rows of 128B each), 4 per wave ----
#pragma unroll
        for (int c = 0; c < 4; c++) {
            const int ch = wv * 4 + c;
            const int row = ch * 8 + aRowIn;
            gl_lds16(X + (size_t)(mblk + row) * E_DIM + k0 + aSrcE, sA + ch * 1024);
        }
        // ---- stage B: 8 chunks x 1KB (16 rows of 64B each), 2 per wave ----
#pragma unroll
        for (int c = 0; c < 2; c++) {
            const int ch = wv * 2 + c;
            const int row = ch * 16 + bRowIn;
            gl_lds16(Wb + (size_t)(nblk + row) * E_DIM + k0 + bSrcE, sB + ch * 1024);
        }
        __syncthreads();   // compiler drains vmcnt before barrier

        bf16x8 va[4], vb[4];
#pragma unroll
        for (int i = 0; i < 4; i++) {
            const int row = wr * 64 + i * 16 + r15;
            const char* base = sA + row * 128;
            const float4 a0 = *reinterpret_cast<const float4*>(base + ((g * 32) ^ swA));
            const float4 a1 = *reinterpret_cast<const float4*>(base + ((g * 32 + 16) ^ swA));
            va[i] = cvt8(a0, a1);
        }
#pragma unroll
        for (int j = 0; j < 4; j++) {
            const int n = wc * 64 + j * 16 + r15;
            vb[j] = *reinterpret_cast<const bf16x8*>(sB + n * 64 + ((g * 16) ^ swB));
        }
#pragma unroll
        for (int i = 0; i < 4; i++)
#pragma unroll
            for (int j = 0; j < 4; j++)
                acc[i][j] = __builtin_amdgcn_mfma_f32_16x16x32_bf16(va[i], vb[j], acc[i][j], 0, 0, 0);
    }

    // ---- epilogue: C row = (lane>>4)*4 + reg, col = lane&15 (m89 mapping) ----
#pragma unroll
    for (int j = 0; j < 4; j++) {
        const int col = nblk + wc * 64 + j * 16 + r15;
        const float bj = bias[col];
#pragma unroll
        for (int i = 0; i < 4; i++) {
            const int row0 = mblk + wr * 64 + i * 16 + g * 4;
#pragma unroll
            for (int r = 0; r < 4; r++) {
                float v = acc[i][j][r] + bj;
                if (p < 2) v = fmaxf(v, 0.0f);
                if (p == 0) Of[(size_t)(row0 + r) * E_DIM + col] = v;
                else        Ob[(size_t)(row0 + r) * E_DIM + col] = f2bf(v);
            }
        }
    }
}

// ---------------- kv[head][d][m] batched tiled GEMM --------------------------
__global__ __launch_bounds__(256) void k_kv2(
    const ushortt* __restrict__ Kb, const ushortt* __restrict__ Vb,
    float* __restrict__ kv)
{
    __shared__ float sk[KV_LT][128];   // feature-mapped K tile
    __shared__ float sv[KV_LT][64];    // V tile

    const int head = blockIdx.x;
    const int b = head >> 4, hh = head & 15;
    const int t = threadIdx.x;
    const int mq = t & 7;              // m base = mq*8
    const int dq = t >> 3;             // d base = dq*4
    const int l0base = blockIdx.y * KV_LCH;

    float acc[4][8];
    float ksum[4];
#pragma unroll
    for (int i = 0; i < 4; i++) {
        ksum[i] = 0.0f;
#pragma unroll
        for (int j = 0; j < 8; j++) acc[i][j] = 0.0f;
    }

    const size_t headoff = (size_t)hh * 64;

    for (int l0 = l0base; l0 < l0base + KV_LCH; l0 += KV_LT) {
        __syncthreads();
#pragma unroll
        for (int i = 0; i < 2; i++) {
            const int j = t + 256 * i;         // 0..511
            const int l = j >> 4;              // 0..31
            const int c4 = (j & 15) << 2;      // 0,4,...,60
            const size_t rowb = ((size_t)(l0 + l) * B_DIM + b) * E_DIM + headoff;
            const uint2 kraw = *reinterpret_cast<const uint2*>(Kb + rowb + c4);
            const uint2 vraw = *reinterpret_cast<const uint2*>(Vb + rowb + c4);
            const float ang = 1.5707963267948966f * (float)(l0 + l + 1) * (1.0f / 4096.0f);
            const float sn = sinf(ang), cs = cosf(ang);
            const float k0 = bf2f((ushortt)(kraw.x & 0xffffu));
            const float k1 = bf2f((ushortt)(kraw.x >> 16));
            const float k2 = bf2f((ushortt)(kraw.y & 0xffffu));
            const float k3 = bf2f((ushortt)(kraw.y >> 16));
            *reinterpret_cast<float4*>(&sk[l][c4]) =
                make_float4(sn * k0, sn * k1, sn * k2, sn * k3);
            *reinterpret_cast<float4*>(&sk[l][64 + c4]) =
                make_float4(cs * k0, cs * k1, cs * k2, cs * k3);
            *reinterpret_cast<float4*>(&sv[l][c4]) =
                make_float4(bf2f((ushortt)(vraw.x & 0xffffu)),
                            bf2f((ushortt)(vraw.x >> 16)),
                            bf2f((ushortt)(vraw.y & 0xffffu)),
                            bf2f((ushortt)(vraw.y >> 16)));
        }
        __syncthreads();
#pragma unroll 8
        for (int l = 0; l < KV_LT; l++) {
            const float4 a4 = *reinterpret_cast<const float4*>(&sk[l][dq << 2]);
            const float4 v0 = *reinterpret_cast<const float4*>(&sv[l][mq << 3]);
            const float4 v1 = *reinterpret_cast<const float4*>(&sv[l][(mq << 3) + 4]);
            const float av[4] = { a4.x, a4.y, a4.z, a4.w };
            const float vv[8] = { v0.x, v0.y, v0.z, v0.w, v1.x, v1.y, v1.z, v1.w };
#pragma unroll
            for (int i = 0; i < 4; i++) {
#pragma unroll
                for (int j = 0; j < 8; j++) acc[i][j] += av[i] * vv[j];
                ksum[i] += av[i];
            }
        }
    }

    float* dst = kv + (size_t)head * (128 * 65);
    const int d0 = dq << 2, m0 = mq << 3;
#pragma unroll
    for (int i = 0; i < 4; i++) {
#pragma unroll
        for (int j = 0; j < 8; j++)
            atomicAdd(&dst[(d0 + i) * 65 + m0 + j], acc[i][j]);
        if (mq == 0)
            atomicAdd(&dst[(d0 + i) * 65 + 64], ksum[i]);
    }
}

// ---------------- out = (q_ . kv) / max(q_ . ksum, eps) ----------------------
__global__ __launch_bounds__(256) void k_attn_s(
    float* qout, const float* __restrict__ kv)
{
    __shared__ float qs[256];
    const int t = threadIdx.x;
    const size_t idx = (size_t)blockIdx.x * 256 + t;
    const int l = (int)(idx >> 12);          // B*E = 4096
    const int rem = (int)(idx & 4095);
    const int b = rem >> 10;
    const int e = rem & 1023;
    const int hh = e >> 6;
    const int m = e & 63;
    const int head = b * 16 + hh;

    qs[t] = qout[idx];                       // relu'd q (f32) from k_gemm
    __syncthreads();

    const float ang = 1.5707963267948966f * (float)(l + 1) * (1.0f / 4096.0f);
    const float s = sinf(ang), c = cosf(ang);
    const float* kvh = kv + (size_t)head * 128 * 65;
    const int qbase = t & 192;               // head-slice base within block

    float numer = 0.0f, den = 0.0f;
#pragma unroll 8
    for (int dd = 0; dd < 64; ++dd) {
        const float qv = qs[qbase + dd];
        numer += qv * (s * kvh[dd * 65 + m] + c * kvh[(dd + 64) * 65 + m]);
        den   += qv * (s * kvh[dd * 65 + 64] + c * kvh[(dd + 64) * 65 + 64]);
    }
    const float z = 1.0f / fmaxf(den, 1e-4f);
    qout[idx] = numer * z;                   // f32 output
}

extern "C" void kernel_launch(void* const* d_in, const int* in_sizes, int n_in,
                              void* d_out, int out_size, void* d_ws, size_t ws_size,
                              hipStream_t stream) {
    (void)in_sizes; (void)n_in; (void)out_size; (void)ws_size;
    const float* xq = (const float*)d_in[0];
    const float* xk = (const float*)d_in[1];
    const float* xv = (const float*)d_in[2];
    const float* wq = (const float*)d_in[3];
    const float* bq = (const float*)d_in[4];
    const float* wk = (const float*)d_in[5];
    const float* bk = (const float*)d_in[6];
    const float* wv = (const float*)d_in[7];
    const float* bv = (const float*)d_in[8];
    float* out = (float*)d_out;  // f32; doubles as Q-projection destination

    char* ws = (char*)d_ws;
    // ws layout (bytes): Kb 33.55MB | Vb 33.55MB | {Wb 2MB / kv 2.13MB aliased}
    // total 69.2MB, identical footprint to round 8. Wb used only in proj phase,
    // kv only after; stream order makes the alias safe.
    ushortt* Kb = (ushortt*)(ws);
    ushortt* Vb = (ushortt*)(ws + 33554432);
    ushortt* Wb = (ushortt*)(ws + 67108864);
    float* kv = (float*)(ws + 67108864);

    dim3 blk(256);
    k_cvtW<<<dim3(1024), blk, 0, stream>>>(wq, Wb);
    k_gemm<<<dim3(1024), blk, 0, stream>>>(xq, Wb, bq, out, (ushortt*)nullptr, 0);
    k_cvtW<<<dim3(1024), blk, 0, stream>>>(wk, Wb);
    k_gemm<<<dim3(1024), blk, 0, stream>>>(xk, Wb, bk, (float*)nullptr, Kb, 1);
    k_cvtW<<<dim3(1024), blk, 0, stream>>>(wv, Wb);
    k_gemm<<<dim3(1024), blk, 0, stream>>>(xv, Wb, bv, (float*)nullptr, Vb, 2);
    hipMemsetAsync(kv, 0, (size_t)64 * 128 * 65 * sizeof(float), stream);
    k_kv2<<<dim3(64, KV_CH), blk, 0, stream>>>(Kb, Vb, kv);
    k_attn_s<<<dim3(65536), blk, 0, stream>>>(out, kv);
}

// Round 3
// 725.540 us; speedup vs baseline: 9.0356x; 1.5511x over previous
//
#include <hip/hip_runtime.h>
#include <hip/hip_bf16.h>

// CosformerAttention: L=4096, B=4, E=1024, H=16, HD=64, n=B*H=64 heads.
// Round 10: LDS-tiled f32 attn GEMM (was 1-thread-per-elem L2-latency-bound,
// 536us, VALUBusy 30%).
//  k_cvtW : W f32 -> bf16, aliases kv region (time-disjoint).
//  k_gemm : unchanged 128x128 bf16 MFMA projection.
//  k_kv2  : unchanged except kv layout split: kvm[head][128][64] + kvd[head][128].
//  k_attn2: per block = (1 head, 32 l-rows): stage kv head-tile (32KB) + sin/cos-
//           mapped q rows (sq[32][132], padded) in LDS; 2x4 register patch per
//           thread; den fused as 5th accumulator; f32 exact.

typedef unsigned short ushortt;
typedef unsigned int u32;
typedef __attribute__((ext_vector_type(8))) short bf16x8;
typedef __attribute__((ext_vector_type(4))) float f32x4;

#define L_DIM 4096
#define B_DIM 4
#define E_DIM 1024

#define KV_CH 8                    // L chunks for k_kv2
#define KV_LCH (L_DIM / KV_CH)     // 512 rows per chunk
#define KV_LT 32                   // l-tile rows staged in LDS

__device__ __forceinline__ ushortt f2bf(float f) {
    union { float f; u32 u; } v; v.f = f;
    u32 u = v.u;
    u += 0x7FFFu + ((u >> 16) & 1u);   // round-to-nearest-even
    return (ushortt)(u >> 16);
}
__device__ __forceinline__ float bf2f(ushortt h) {
    union { u32 u; float f; } v; v.u = ((u32)h) << 16;
    return v.f;
}

__device__ __forceinline__ void gl_lds16(const void* g, void* l) {
    __builtin_amdgcn_global_load_lds(
        (const __attribute__((address_space(1))) unsigned int*)g,
        (__attribute__((address_space(3))) unsigned int*)l, 16, 0, 0);
}

// pack 8 f32 -> 8 bf16 (RNE via hw cvt_pk)
__device__ __forceinline__ bf16x8 cvt8(float4 a, float4 b) {
    union { bf16x8 v; __hip_bfloat162 h[4]; } r;
    r.h[0] = __float22bfloat162_rn(make_float2(a.x, a.y));
    r.h[1] = __float22bfloat162_rn(make_float2(a.z, a.w));
    r.h[2] = __float22bfloat162_rn(make_float2(b.x, b.y));
    r.h[3] = __float22bfloat162_rn(make_float2(b.z, b.w));
    return r.v;
}

// ---------------- W f32 -> bf16 converter ------------------------------------
__global__ __launch_bounds__(256) void k_cvtW(
    const float* __restrict__ W, ushortt* __restrict__ Wb)
{
    const int i = (blockIdx.x * 256 + threadIdx.x) * 4;   // 1M elems
    const float4 v = *reinterpret_cast<const float4*>(W + i);
    ushortt o[4] = { f2bf(v.x), f2bf(v.y), f2bf(v.z), f2bf(v.w) };
    *reinterpret_cast<uint2*>(Wb + i) = *reinterpret_cast<uint2*>(o);
}

// ---------------- MFMA projection GEMM ---------------------------------------
// Y[m][n] = relu?(sum_k X[m][k]*W[n][k] + b[n]); M=16384, N=1024, K=1024.
// Tile 128x128, BK=32. 4 waves (2x2), each wave 64x64 via 4x4 of 16x16x32 MFMA.
__global__ __launch_bounds__(256) void k_gemm(
    const float* __restrict__ X, const ushortt* __restrict__ Wb,
    const float* __restrict__ bias,
    float* __restrict__ Of, ushortt* __restrict__ Ob, const int p)
{
    __shared__ char sA[16384];     // 128 x 128B
    __shared__ char sB[8192];      // 128 x 64B

    const int t = threadIdx.x;
    const int ln = t & 63;
    const int wv = t >> 6;
    const int wr = wv >> 1, wc = wv & 1;

    // XCD-aware bijective swizzle: 1024 blocks, xcd = orig%8 gets 128 contiguous.
    const int orig = blockIdx.x;
    const int bid = (orig & 7) * 128 + (orig >> 3);
    const int mblk = (bid >> 3) * 128;
    const int nblk = (bid & 7) * 128;

    f32x4 acc[4][4];
#pragma unroll
    for (int i = 0; i < 4; i++)
#pragma unroll
        for (int j = 0; j < 4; j++) acc[i][j] = (f32x4){0.f, 0.f, 0.f, 0.f};

    // staging lane constants
    const int aRowIn = ln >> 3;                               // row within 8-row chunk
    const int aSrcE  = ((ln & 7) ^ aRowIn) << 2;              // f32 elems (pre-swizzled)
    const int bRowIn = ln >> 2;                               // row within 16-row chunk
    const int bSrcE  = (((ln & 3) ^ ((ln >> 3) & 3))) << 3;   // bf16 elems (pre-swizzled)

    // frag-read lane constants
    const int g   = ln >> 4;
    const int r15 = ln & 15;
    const int swA = (ln & 7) << 4;          // = ((row&7)<<4), row = ...+(ln&15)
    const int swB = ((ln >> 1) & 3) << 4;   // = (((n>>1)&3)<<4)

    for (int k0 = 0; k0 < 1024; k0 += 32) {
        __syncthreads();
        // ---- stage A: 16 chunks x 1KB (8 rows of 128B each), 4 per wave ----
#pragma unroll
        for (int c = 0; c < 4; c++) {
            const int ch = wv * 4 + c;
            const int row = ch * 8 + aRowIn;
            gl_lds16(X + (size_t)(mblk + row) * E_DIM + k0 + aSrcE, sA + ch * 1024);
        }
        // ---- stage B: 8 chunks x 1KB (16 rows of 64B each), 2 per wave ----
#pragma unroll
        for (int c = 0; c < 2; c++) {
            const int ch = wv * 2 + c;
            const int row = ch * 16 + bRowIn;
            gl_lds16(Wb + (size_t)(nblk + row) * E_DIM + k0 + bSrcE, sB + ch * 1024);
        }
        __syncthreads();   // compiler drains vmcnt before barrier

        bf16x8 va[4], vb[4];
#pragma unroll
        for (int i = 0; i < 4; i++) {
            const int row = wr * 64 + i * 16 + r15;
            const char* base = sA + row * 128;
            const float4 a0 = *reinterpret_cast<const float4*>(base + ((g * 32) ^ swA));
            const float4 a1 = *reinterpret_cast<const float4*>(base + ((g * 32 + 16) ^ swA));
            va[i] = cvt8(a0, a1);
        }
#pragma unroll
        for (int j = 0; j < 4; j++) {
            const int n = wc * 64 + j * 16 + r15;
            vb[j] = *reinterpret_cast<const bf16x8*>(sB + n * 64 + ((g * 16) ^ swB));
        }
#pragma unroll
        for (int i = 0; i < 4; i++)
#pragma unroll
            for (int j = 0; j < 4; j++)
                acc[i][j] = __builtin_amdgcn_mfma_f32_16x16x32_bf16(va[i], vb[j], acc[i][j], 0, 0, 0);
    }

    // ---- epilogue: C row = (lane>>4)*4 + reg, col = lane&15 (m89 mapping) ----
#pragma unroll
    for (int j = 0; j < 4; j++) {
        const int col = nblk + wc * 64 + j * 16 + r15;
        const float bj = bias[col];
#pragma unroll
        for (int i = 0; i < 4; i++) {
            const int row0 = mblk + wr * 64 + i * 16 + g * 4;
#pragma unroll
            for (int r = 0; r < 4; r++) {
                float v = acc[i][j][r] + bj;
                if (p < 2) v = fmaxf(v, 0.0f);
                if (p == 0) Of[(size_t)(row0 + r) * E_DIM + col] = v;
                else        Ob[(size_t)(row0 + r) * E_DIM + col] = f2bf(v);
            }
        }
    }
}

// ---------------- kv batched tiled GEMM --------------------------------------
// kvm[head][d][m] (stride 64) = sum_l sk[l][d]*v[l][m];  kvd[head][d] = sum_l sk[l][d]
__global__ __launch_bounds__(256) void k_kv2(
    const ushortt* __restrict__ Kb, const ushortt* __restrict__ Vb,
    float* __restrict__ kvm, float* __restrict__ kvd)
{
    __shared__ float sk[KV_LT][128];   // feature-mapped K tile
    __shared__ float sv[KV_LT][64];    // V tile

    const int head = blockIdx.x;
    const int b = head >> 4, hh = head & 15;
    const int t = threadIdx.x;
    const int mq = t & 7;              // m base = mq*8
    const int dq = t >> 3;             // d base = dq*4
    const int l0base = blockIdx.y * KV_LCH;

    float acc[4][8];
    float ksum[4];
#pragma unroll
    for (int i = 0; i < 4; i++) {
        ksum[i] = 0.0f;
#pragma unroll
        for (int j = 0; j < 8; j++) acc[i][j] = 0.0f;
    }

    const size_t headoff = (size_t)hh * 64;

    for (int l0 = l0base; l0 < l0base + KV_LCH; l0 += KV_LT) {
        __syncthreads();
#pragma unroll
        for (int i = 0; i < 2; i++) {
            const int j = t + 256 * i;         // 0..511
            const int l = j >> 4;              // 0..31
            const int c4 = (j & 15) << 2;      // 0,4,...,60
            const size_t rowb = ((size_t)(l0 + l) * B_DIM + b) * E_DIM + headoff;
            const uint2 kraw = *reinterpret_cast<const uint2*>(Kb + rowb + c4);
            const uint2 vraw = *reinterpret_cast<const uint2*>(Vb + rowb + c4);
            const float ang = 1.5707963267948966f * (float)(l0 + l + 1) * (1.0f / 4096.0f);
            const float sn = sinf(ang), cs = cosf(ang);
            const float k0 = bf2f((ushortt)(kraw.x & 0xffffu));
            const float k1 = bf2f((ushortt)(kraw.x >> 16));
            const float k2 = bf2f((ushortt)(kraw.y & 0xffffu));
            const float k3 = bf2f((ushortt)(kraw.y >> 16));
            *reinterpret_cast<float4*>(&sk[l][c4]) =
                make_float4(sn * k0, sn * k1, sn * k2, sn * k3);
            *reinterpret_cast<float4*>(&sk[l][64 + c4]) =
                make_float4(cs * k0, cs * k1, cs * k2, cs * k3);
            *reinterpret_cast<float4*>(&sv[l][c4]) =
                make_float4(bf2f((ushortt)(vraw.x & 0xffffu)),
                            bf2f((ushortt)(vraw.x >> 16)),
                            bf2f((ushortt)(vraw.y & 0xffffu)),
                            bf2f((ushortt)(vraw.y >> 16)));
        }
        __syncthreads();
#pragma unroll 8
        for (int l = 0; l < KV_LT; l++) {
            const float4 a4 = *reinterpret_cast<const float4*>(&sk[l][dq << 2]);
            const float4 v0 = *reinterpret_cast<const float4*>(&sv[l][mq << 3]);
            const float4 v1 = *reinterpret_cast<const float4*>(&sv[l][(mq << 3) + 4]);
            const float av[4] = { a4.x, a4.y, a4.z, a4.w };
            const float vv[8] = { v0.x, v0.y, v0.z, v0.w, v1.x, v1.y, v1.z, v1.w };
#pragma unroll
            for (int i = 0; i < 4; i++) {
#pragma unroll
                for (int j = 0; j < 8; j++) acc[i][j] += av[i] * vv[j];
                ksum[i] += av[i];
            }
        }
    }

    float* dstm = kvm + (size_t)head * (128 * 64);
    float* dstd = kvd + (size_t)head * 128;
    const int d0 = dq << 2, m0 = mq << 3;
#pragma unroll
    for (int i = 0; i < 4; i++) {
#pragma unroll
        for (int j = 0; j < 8; j++)
            atomicAdd(&dstm[(d0 + i) * 64 + m0 + j], acc[i][j]);
        if (mq == 0)
            atomicAdd(&dstd[d0 + i], ksum[i]);
    }
}

// ---------------- attn: out = (q_ . kv) / max(q_ . ksum, eps) ----------------
// Block = (head, 32 l-rows). LDS: skv[128][64] 32KB + skd[128] + sq[32][132]
// (pad 132: conflict-free, 528B row = 16B-aligned). Thread patch: 2 rows x 4 m.
// In-place safe: block stages its own qout slice, barrier, then overwrites it.
__global__ __launch_bounds__(256) void k_attn2(
    float* qout, const float* __restrict__ kvm, const float* __restrict__ kvd)
{
    __shared__ float skv[128][64];
    __shared__ float skd[128];
    __shared__ float sq[32][132];

    const int t = threadIdx.x;
    const int head = blockIdx.x;           // 0..63
    const int b = head >> 4, hh = head & 15;
    const int l0 = blockIdx.y * 32;

    const float* kvh = kvm + (size_t)head * (128 * 64);

    // stage kv head-tile: 128 rows x 16 float4 (aligned, coalesced)
#pragma unroll
    for (int c = 0; c < 8; c++) {
        const int idx = t + 256 * c;       // 0..2047
        const int d = idx >> 4, m4 = (idx & 15) << 2;
        *reinterpret_cast<float4*>(&skv[d][m4]) =
            *reinterpret_cast<const float4*>(kvh + d * 64 + m4);
    }
    if (t < 128) skd[t] = kvd[(size_t)head * 128 + t];

    // stage q rows with sin/cos feature map folded in
    const size_t qbase = ((size_t)l0 * B_DIM + b) * E_DIM + (size_t)hh * 64;
#pragma unroll
    for (int c = 0; c < 2; c++) {
        const int idx = t + 256 * c;       // 0..511
        const int l = idx >> 4, q4 = (idx & 15) << 2;
        const float4 v = *reinterpret_cast<const float4*>(
            qout + qbase + (size_t)l * (B_DIM * E_DIM) + q4);
        const float ang = 1.5707963267948966f * (float)(l0 + l + 1) * (1.0f / 4096.0f);
        const float sn = sinf(ang), cs = cosf(ang);
        *reinterpret_cast<float4*>(&sq[l][q4]) =
            make_float4(sn * v.x, sn * v.y, sn * v.z, sn * v.w);
        *reinterpret_cast<float4*>(&sq[l][64 + q4]) =
            make_float4(cs * v.x, cs * v.y, cs * v.z, cs * v.w);
    }
    __syncthreads();

    const int tx = t & 15, ty = t >> 4;
    const int r = ty * 2, m0 = tx * 4;

    float4 acc[2] = { make_float4(0.f, 0.f, 0.f, 0.f), make_float4(0.f, 0.f, 0.f, 0.f) };
    float accd[2] = { 0.f, 0.f };

#pragma unroll 4
    for (int d0 = 0; d0 < 128; d0 += 4) {
        const float4 kd4 = *reinterpret_cast<const float4*>(&skd[d0]);
        float4 qv[2];
#pragma unroll
        for (int i = 0; i < 2; i++)
            qv[i] = *reinterpret_cast<const float4*>(&sq[r + i][d0]);
#pragma unroll
        for (int dd = 0; dd < 4; dd++) {
            const float4 kvv = *reinterpret_cast<const float4*>(&skv[d0 + dd][m0]);
            const float kdv = (dd == 0) ? kd4.x : (dd == 1) ? kd4.y : (dd == 2) ? kd4.z : kd4.w;
#pragma unroll
            for (int i = 0; i < 2; i++) {
                const float qs = (dd == 0) ? qv[i].x : (dd == 1) ? qv[i].y
                               : (dd == 2) ? qv[i].z : qv[i].w;
                acc[i].x += qs * kvv.x;
                acc[i].y += qs * kvv.y;
                acc[i].z += qs * kvv.z;
                acc[i].w += qs * kvv.w;
                accd[i] += qs * kdv;
            }
        }
    }

#pragma unroll
    for (int i = 0; i < 2; i++) {
        const float z = 1.0f / fmaxf(accd[i], 1e-4f);
        float4 vo = make_float4(acc[i].x * z, acc[i].y * z, acc[i].z * z, acc[i].w * z);
        *reinterpret_cast<float4*>(
            qout + qbase + (size_t)(r + i) * (B_DIM * E_DIM) + m0) = vo;
    }
}

extern "C" void kernel_launch(void* const* d_in, const int* in_sizes, int n_in,
                              void* d_out, int out_size, void* d_ws, size_t ws_size,
                              hipStream_t stream) {
    (void)in_sizes; (void)n_in; (void)out_size; (void)ws_size;
    const float* xq = (const float*)d_in[0];
    const float* xk = (const float*)d_in[1];
    const float* xv = (const float*)d_in[2];
    const float* wq = (const float*)d_in[3];
    const float* bq = (const float*)d_in[4];
    const float* wk = (const float*)d_in[5];
    const float* bk = (const float*)d_in[6];
    const float* wv = (const float*)d_in[7];
    const float* bv = (const float*)d_in[8];
    float* out = (float*)d_out;  // f32; doubles as Q-projection destination

    char* ws = (char*)d_ws;
    // ws layout (bytes): Kb 33.55MB | Vb 33.55MB | {Wb 2MB / kvm 2.0MB + kvd 32KB}
    // total 69.24MB, identical footprint to round 9. Wb used only in proj phase.
    ushortt* Kb = (ushortt*)(ws);
    ushortt* Vb = (ushortt*)(ws + 33554432);
    ushortt* Wb = (ushortt*)(ws + 67108864);
    float* kvm = (float*)(ws + 67108864);
    float* kvd = (float*)(ws + 67108864 + 2097152);

    dim3 blk(256);
    k_cvtW<<<dim3(1024), blk, 0, stream>>>(wq, Wb);
    k_gemm<<<dim3(1024), blk, 0, stream>>>(xq, Wb, bq, out, (ushortt*)nullptr, 0);
    k_cvtW<<<dim3(1024), blk, 0, stream>>>(wk, Wb);
    k_gemm<<<dim3(1024), blk, 0, stream>>>(xk, Wb, bk, (float*)nullptr, Kb, 1);
    k_cvtW<<<dim3(1024), blk, 0, stream>>>(wv, Wb);
    k_gemm<<<dim3(1024), blk, 0, stream>>>(xv, Wb, bv, (float*)nullptr, Vb, 2);
    hipMemsetAsync(kvm, 0, (size_t)(2097152 + 32768), stream);
    k_kv2<<<dim3(64, KV_CH), blk, 0, stream>>>(Kb, Vb, kvm, kvd);
    k_attn2<<<dim3(64, 128), blk, 0, stream>>>(out, kvm, kvd);
}

// Round 4
// 564.149 us; speedup vs baseline: 11.6205x; 1.2861x over previous
//
#include <hip/hip_runtime.h>
#include <hip/hip_bf16.h>

// CosformerAttention: L=4096, B=4, E=1024, H=16, HD=64, n=B*H=64 heads.
// Round 11: kill kv atomics (135MB HBM atomic traffic -> 17MB plain stores)
// by reordering the pipeline so d_out is free as partial scratch; pre-convert
// X to bf16 so the GEMMs are pure-bf16 both operands (no in-loop cvt, 4+4
// ds_read_b128, 16KB LDS).
// Order: cvtW(k),cvtX(k),gemm->Kb | cvtW(v),cvtX(v),gemm->Vb |
//        kv3 -> partials (d_out) | kvred -> kvm/kvd (ws, over dead Wb) |
//        cvtW(q)->dead Vb, cvtX(q)->dead Kb, gemm->d_out | attn2 in-place.

typedef unsigned short ushortt;
typedef unsigned int u32;
typedef __attribute__((ext_vector_type(8))) short bf16x8;
typedef __attribute__((ext_vector_type(4))) float f32x4;

#define L_DIM 4096
#define B_DIM 4
#define E_DIM 1024

#define KV_CH 8                    // L chunks for k_kv3
#define KV_LCH (L_DIM / KV_CH)     // 512 rows per chunk
#define KV_LT 32                   // l-tile rows staged in LDS

__device__ __forceinline__ ushortt f2bf(float f) {
    union { float f; u32 u; } v; v.f = f;
    u32 u = v.u;
    u += 0x7FFFu + ((u >> 16) & 1u);   // round-to-nearest-even
    return (ushortt)(u >> 16);
}
__device__ __forceinline__ float bf2f(ushortt h) {
    union { u32 u; float f; } v; v.u = ((u32)h) << 16;
    return v.f;
}

__device__ __forceinline__ void gl_lds16(const void* g, void* l) {
    __builtin_amdgcn_global_load_lds(
        (const __attribute__((address_space(1))) unsigned int*)g,
        (__attribute__((address_space(3))) unsigned int*)l, 16, 0, 0);
}

// ---------------- f32 -> bf16 converters -------------------------------------
__global__ __launch_bounds__(256) void k_cvtW(
    const float* __restrict__ W, ushortt* __restrict__ Wb)
{
    const int i = (blockIdx.x * 256 + threadIdx.x) * 4;   // 1M elems
    const float4 v = *reinterpret_cast<const float4*>(W + i);
    ushortt o[4] = { f2bf(v.x), f2bf(v.y), f2bf(v.z), f2bf(v.w) };
    *reinterpret_cast<uint2*>(Wb + i) = *reinterpret_cast<uint2*>(o);
}

__global__ __launch_bounds__(256) void k_cvtX(
    const float* __restrict__ X, ushortt* __restrict__ Xb)
{
    const int i = (blockIdx.x * 256 + threadIdx.x) * 4;   // 16.8M elems
    const float4 v = *reinterpret_cast<const float4*>(X + i);
    ushortt o[4] = { f2bf(v.x), f2bf(v.y), f2bf(v.z), f2bf(v.w) };
    *reinterpret_cast<uint2*>(Xb + i) = *reinterpret_cast<uint2*>(o);
}

// ---------------- MFMA projection GEMM (bf16 A and B) ------------------------
// Y[m][n] = relu?(sum_k Xb[m][k]*Wb[n][k] + b[n]); M=16384, N=1024, K=1024.
// Tile 128x128, BK=32. 4 waves (2x2), each wave 64x64 via 4x4 of 16x16x32 MFMA.
// Both operands: 128 rows x 64B in LDS, XOR swizzle key ((row>>1)&3)<<4 applied
// via pre-swizzled global source (linear gl_lds dest) + same XOR on ds_read.
__global__ __launch_bounds__(256) void k_gemmB(
    const ushortt* __restrict__ Xb, const ushortt* __restrict__ Wb,
    const float* __restrict__ bias,
    float* __restrict__ Of, ushortt* __restrict__ Ob, const int p)
{
    __shared__ char sA[8192];      // 128 x 64B
    __shared__ char sB[8192];      // 128 x 64B

    const int t = threadIdx.x;
    const int ln = t & 63;
    const int wv = t >> 6;
    const int wr = wv >> 1, wc = wv & 1;

    // XCD-aware bijective swizzle: 1024 blocks, xcd = orig%8 gets 128 contiguous.
    const int orig = blockIdx.x;
    const int bid = (orig & 7) * 128 + (orig >> 3);
    const int mblk = (bid >> 3) * 128;
    const int nblk = (bid & 7) * 128;

    f32x4 acc[4][4];
#pragma unroll
    for (int i = 0; i < 4; i++)
#pragma unroll
        for (int j = 0; j < 4; j++) acc[i][j] = (f32x4){0.f, 0.f, 0.f, 0.f};

    // staging lane constants (16 rows of 64B per 1KB chunk)
    const int rowIn = ln >> 2;                              // 0..15
    const int srcE  = ((ln & 3) ^ ((ln >> 3) & 3)) << 3;    // bf16 elems, pre-swizzled

    // frag-read lane constants
    const int g   = ln >> 4;
    const int r15 = ln & 15;
    const int sw  = ((r15 >> 1) & 3) << 4;                  // ((row>>1)&3)<<4

    for (int k0 = 0; k0 < 1024; k0 += 32) {
        __syncthreads();
        // ---- stage A and B: 8 chunks x 1KB each, 2 per wave per matrix ----
#pragma unroll
        for (int c = 0; c < 2; c++) {
            const int ch = wv * 2 + c;
            const int row = ch * 16 + rowIn;
            gl_lds16(Xb + (size_t)(mblk + row) * E_DIM + k0 + srcE, sA + ch * 1024);
            gl_lds16(Wb + (size_t)(nblk + row) * E_DIM + k0 + srcE, sB + ch * 1024);
        }
        __syncthreads();   // compiler drains vmcnt before barrier

        bf16x8 va[4], vb[4];
#pragma unroll
        for (int i = 0; i < 4; i++) {
            const int row = wr * 64 + i * 16 + r15;
            va[i] = *reinterpret_cast<const bf16x8*>(sA + row * 64 + ((g * 16) ^ sw));
        }
#pragma unroll
        for (int j = 0; j < 4; j++) {
            const int n = wc * 64 + j * 16 + r15;
            vb[j] = *reinterpret_cast<const bf16x8*>(sB + n * 64 + ((g * 16) ^ sw));
        }
#pragma unroll
        for (int i = 0; i < 4; i++)
#pragma unroll
            for (int j = 0; j < 4; j++)
                acc[i][j] = __builtin_amdgcn_mfma_f32_16x16x32_bf16(va[i], vb[j], acc[i][j], 0, 0, 0);
    }

    // ---- epilogue: C row = (lane>>4)*4 + reg, col = lane&15 (m89 mapping) ----
#pragma unroll
    for (int j = 0; j < 4; j++) {
        const int col = nblk + wc * 64 + j * 16 + r15;
        const float bj = bias[col];
#pragma unroll
        for (int i = 0; i < 4; i++) {
            const int row0 = mblk + wr * 64 + i * 16 + g * 4;
#pragma unroll
            for (int r = 0; r < 4; r++) {
                float v = acc[i][j][r] + bj;
                if (p < 2) v = fmaxf(v, 0.0f);
                if (p == 0) Of[(size_t)(row0 + r) * E_DIM + col] = v;
                else        Ob[(size_t)(row0 + r) * E_DIM + col] = f2bf(v);
            }
        }
    }
}

// ---------------- kv partials: pm[ch][head][128][64], pd[ch][head][128] ------
// pm = sum_{l in chunk} sk[l][d]*v[l][m]; pd = sum sk[l][d]. Plain stores.
__global__ __launch_bounds__(256) void k_kv3(
    const ushortt* __restrict__ Kb, const ushortt* __restrict__ Vb,
    float* __restrict__ pm, float* __restrict__ pd)
{
    __shared__ float sk[KV_LT][128];   // feature-mapped K tile
    __shared__ float sv[KV_LT][64];    // V tile

    const int head = blockIdx.x;
    const int b = head >> 4, hh = head & 15;
    const int t = threadIdx.x;
    const int mq = t & 7;              // m base = mq*8
    const int dq = t >> 3;             // d base = dq*4
    const int l0base = blockIdx.y * KV_LCH;

    float acc[4][8];
    float ksum[4];
#pragma unroll
    for (int i = 0; i < 4; i++) {
        ksum[i] = 0.0f;
#pragma unroll
        for (int j = 0; j < 8; j++) acc[i][j] = 0.0f;
    }

    const size_t headoff = (size_t)hh * 64;

    for (int l0 = l0base; l0 < l0base + KV_LCH; l0 += KV_LT) {
        __syncthreads();
#pragma unroll
        for (int i = 0; i < 2; i++) {
            const int j = t + 256 * i;         // 0..511
            const int l = j >> 4;              // 0..31
            const int c4 = (j & 15) << 2;      // 0,4,...,60
            const size_t rowb = ((size_t)(l0 + l) * B_DIM + b) * E_DIM + headoff;
            const uint2 kraw = *reinterpret_cast<const uint2*>(Kb + rowb + c4);
            const uint2 vraw = *reinterpret_cast<const uint2*>(Vb + rowb + c4);
            const float ang = 1.5707963267948966f * (float)(l0 + l + 1) * (1.0f / 4096.0f);
            const float sn = sinf(ang), cs = cosf(ang);
            const float k0 = bf2f((ushortt)(kraw.x & 0xffffu));
            const float k1 = bf2f((ushortt)(kraw.x >> 16));
            const float k2 = bf2f((ushortt)(kraw.y & 0xffffu));
            const float k3 = bf2f((ushortt)(kraw.y >> 16));
            *reinterpret_cast<float4*>(&sk[l][c4]) =
                make_float4(sn * k0, sn * k1, sn * k2, sn * k3);
            *reinterpret_cast<float4*>(&sk[l][64 + c4]) =
                make_float4(cs * k0, cs * k1, cs * k2, cs * k3);
            *reinterpret_cast<float4*>(&sv[l][c4]) =
                make_float4(bf2f((ushortt)(vraw.x & 0xffffu)),
                            bf2f((ushortt)(vraw.x >> 16)),
                            bf2f((ushortt)(vraw.y & 0xffffu)),
                            bf2f((ushortt)(vraw.y >> 16)));
        }
        __syncthreads();
#pragma unroll 8
        for (int l = 0; l < KV_LT; l++) {
            const float4 a4 = *reinterpret_cast<const float4*>(&sk[l][dq << 2]);
            const float4 v0 = *reinterpret_cast<const float4*>(&sv[l][mq << 3]);
            const float4 v1 = *reinterpret_cast<const float4*>(&sv[l][(mq << 3) + 4]);
            const float av[4] = { a4.x, a4.y, a4.z, a4.w };
            const float vv[8] = { v0.x, v0.y, v0.z, v0.w, v1.x, v1.y, v1.z, v1.w };
#pragma unroll
            for (int i = 0; i < 4; i++) {
#pragma unroll
                for (int j = 0; j < 8; j++) acc[i][j] += av[i] * vv[j];
                ksum[i] += av[i];
            }
        }
    }

    float* dstm = pm + ((size_t)blockIdx.y * 64 + head) * 8192;   // 128*64
    float* dstd = pd + ((size_t)blockIdx.y * 64 + head) * 128;
    const int d0 = dq << 2, m0 = mq << 3;
#pragma unroll
    for (int i = 0; i < 4; i++) {
        *reinterpret_cast<float4*>(&dstm[(d0 + i) * 64 + m0]) =
            make_float4(acc[i][0], acc[i][1], acc[i][2], acc[i][3]);
        *reinterpret_cast<float4*>(&dstm[(d0 + i) * 64 + m0 + 4]) =
            make_float4(acc[i][4], acc[i][5], acc[i][6], acc[i][7]);
        if (mq == 0) dstd[d0 + i] = ksum[i];
    }
}

// ---------------- reduce partials: kvm[head][128][64], kvd[head][128] --------
__global__ __launch_bounds__(256) void k_kvred(
    const float* __restrict__ pm, const float* __restrict__ pd,
    float* __restrict__ kvm, float* __restrict__ kvd)
{
    const int bid = blockIdx.x, t = threadIdx.x;
    if (bid < 512) {
        const int g = bid * 256 + t;           // float4 index, 131072 total
        const int head = g >> 11, r = g & 2047;
        float4 s = make_float4(0.f, 0.f, 0.f, 0.f);
#pragma unroll
        for (int c = 0; c < KV_CH; c++) {
            const float4 v = reinterpret_cast<const float4*>(pm)[((size_t)(c * 64 + head) << 11) + r];
            s.x += v.x; s.y += v.y; s.z += v.z; s.w += v.w;
        }
        reinterpret_cast<float4*>(kvm)[g] = s;
    } else {
#pragma unroll
        for (int it = 0; it < 8; it++) {
            const int idx = it * 256 + t;      // float4 index, 2048 total
            const int head = idx >> 5, r = idx & 31;
            float4 s = make_float4(0.f, 0.f, 0.f, 0.f);
#pragma unroll
            for (int c = 0; c < KV_CH; c++) {
                const float4 v = reinterpret_cast<const float4*>(pd)[((size_t)(c * 64 + head) << 5) + r];
                s.x += v.x; s.y += v.y; s.z += v.z; s.w += v.w;
            }
            reinterpret_cast<float4*>(kvd)[idx] = s;
        }
    }
}

// ---------------- attn: out = (q_ . kv) / max(q_ . ksum, eps) ----------------
// Block = (head, 32 l-rows). LDS: skv[128][64] 32KB + skd[128] + sq[32][132].
// In-place safe: block stages its own qout slice, barrier, then overwrites it.
__global__ __launch_bounds__(256) void k_attn2(
    float* qout, const float* __restrict__ kvm, const float* __restrict__ kvd)
{
    __shared__ float skv[128][64];
    __shared__ float skd[128];
    __shared__ float sq[32][132];

    const int t = threadIdx.x;
    const int head = blockIdx.x;           // 0..63
    const int b = head >> 4, hh = head & 15;
    const int l0 = blockIdx.y * 32;

    const float* kvh = kvm + (size_t)head * (128 * 64);

#pragma unroll
    for (int c = 0; c < 8; c++) {
        const int idx = t + 256 * c;       // 0..2047
        const int d = idx >> 4, m4 = (idx & 15) << 2;
        *reinterpret_cast<float4*>(&skv[d][m4]) =
            *reinterpret_cast<const float4*>(kvh + d * 64 + m4);
    }
    if (t < 128) skd[t] = kvd[(size_t)head * 128 + t];

    const size_t qbase = ((size_t)l0 * B_DIM + b) * E_DIM + (size_t)hh * 64;
#pragma unroll
    for (int c = 0; c < 2; c++) {
        const int idx = t + 256 * c;       // 0..511
        const int l = idx >> 4, q4 = (idx & 15) << 2;
        const float4 v = *reinterpret_cast<const float4*>(
            qout + qbase + (size_t)l * (B_DIM * E_DIM) + q4);
        const float ang = 1.5707963267948966f * (float)(l0 + l + 1) * (1.0f / 4096.0f);
        const float sn = sinf(ang), cs = cosf(ang);
        *reinterpret_cast<float4*>(&sq[l][q4]) =
            make_float4(sn * v.x, sn * v.y, sn * v.z, sn * v.w);
        *reinterpret_cast<float4*>(&sq[l][64 + q4]) =
            make_float4(cs * v.x, cs * v.y, cs * v.z, cs * v.w);
    }
    __syncthreads();

    const int tx = t & 15, ty = t >> 4;
    const int r = ty * 2, m0 = tx * 4;

    float4 acc[2] = { make_float4(0.f, 0.f, 0.f, 0.f), make_float4(0.f, 0.f, 0.f, 0.f) };
    float accd[2] = { 0.f, 0.f };

#pragma unroll 4
    for (int d0 = 0; d0 < 128; d0 += 4) {
        const float4 kd4 = *reinterpret_cast<const float4*>(&skd[d0]);
        float4 qv[2];
#pragma unroll
        for (int i = 0; i < 2; i++)
            qv[i] = *reinterpret_cast<const float4*>(&sq[r + i][d0]);
#pragma unroll
        for (int dd = 0; dd < 4; dd++) {
            const float4 kvv = *reinterpret_cast<const float4*>(&skv[d0 + dd][m0]);
            const float kdv = (dd == 0) ? kd4.x : (dd == 1) ? kd4.y : (dd == 2) ? kd4.z : kd4.w;
#pragma unroll
            for (int i = 0; i < 2; i++) {
                const float qs = (dd == 0) ? qv[i].x : (dd == 1) ? qv[i].y
                               : (dd == 2) ? qv[i].z : qv[i].w;
                acc[i].x += qs * kvv.x;
                acc[i].y += qs * kvv.y;
                acc[i].z += qs * kvv.z;
                acc[i].w += qs * kvv.w;
                accd[i] += qs * kdv;
            }
        }
    }

#pragma unroll
    for (int i = 0; i < 2; i++) {
        const float z = 1.0f / fmaxf(accd[i], 1e-4f);
        float4 vo = make_float4(acc[i].x * z, acc[i].y * z, acc[i].z * z, acc[i].w * z);
        *reinterpret_cast<float4*>(
            qout + qbase + (size_t)(r + i) * (B_DIM * E_DIM) + m0) = vo;
    }
}

extern "C" void kernel_launch(void* const* d_in, const int* in_sizes, int n_in,
                              void* d_out, int out_size, void* d_ws, size_t ws_size,
                              hipStream_t stream) {
    (void)in_sizes; (void)n_in; (void)out_size; (void)ws_size;
    const float* xq = (const float*)d_in[0];
    const float* xk = (const float*)d_in[1];
    const float* xv = (const float*)d_in[2];
    const float* wq = (const float*)d_in[3];
    const float* bq = (const float*)d_in[4];
    const float* wk = (const float*)d_in[5];
    const float* bk = (const float*)d_in[6];
    const float* wv = (const float*)d_in[7];
    const float* bv = (const float*)d_in[8];
    float* out = (float*)d_out;  // 67MB; free as scratch until Q-proj (runs last)

    char* ws = (char*)d_ws;
    // ws (69.24MB): [0,33.5M) Kb / later Xqb ; [33.5M,67.1M) Vb / later Wqb ;
    // [67.1M, +2.13M) Wb (K/V phase) / later kvm+kvd.
    ushortt* Kb  = (ushortt*)(ws);
    ushortt* Vb  = (ushortt*)(ws + 33554432);
    ushortt* Wb  = (ushortt*)(ws + 67108864);
    float*   kvm = (float*)(ws + 67108864);
    float*   kvd = (float*)(ws + 67108864 + 2097152);
    ushortt* Xqb = (ushortt*)(ws);              // over dead Kb
    ushortt* Wqb = (ushortt*)(ws + 33554432);   // over dead Vb

    // d_out scratch: [0,33.5M) Xkb / later pm+pd ; [33.5M,67.1M) Xvb.
    ushortt* Xkb = (ushortt*)d_out;
    ushortt* Xvb = (ushortt*)((char*)d_out + 33554432);
    float*   pm  = (float*)d_out;                              // 16.78MB
    float*   pd  = (float*)((char*)d_out + 16777216);          // 262KB

    dim3 blk(256);
    // K projection
    k_cvtW<<<dim3(1024), blk, 0, stream>>>(wk, Wb);
    k_cvtX<<<dim3(16384), blk, 0, stream>>>(xk, Xkb);
    k_gemmB<<<dim3(1024), blk, 0, stream>>>(Xkb, Wb, bk, (float*)nullptr, Kb, 1);
    // V projection
    k_cvtW<<<dim3(1024), blk, 0, stream>>>(wv, Wb);
    k_cvtX<<<dim3(16384), blk, 0, stream>>>(xv, Xvb);
    k_gemmB<<<dim3(1024), blk, 0, stream>>>(Xvb, Wb, bv, (float*)nullptr, Vb, 2);
    // kv partials (plain stores into d_out) + reduce into ws (over dead Wb)
    k_kv3<<<dim3(64, KV_CH), blk, 0, stream>>>(Kb, Vb, pm, pd);
    k_kvred<<<dim3(513), blk, 0, stream>>>(pm, pd, kvm, kvd);
    // Q projection (scratch in dead Kb/Vb regions; output fills d_out)
    k_cvtW<<<dim3(1024), blk, 0, stream>>>(wq, Wqb);
    k_cvtX<<<dim3(16384), blk, 0, stream>>>(xq, Xqb);
    k_gemmB<<<dim3(1024), blk, 0, stream>>>(Xqb, Wqb, bq, out, (ushortt*)nullptr, 0);
    // attention epilogue, in-place on d_out
    k_attn2<<<dim3(64, 128), blk, 0, stream>>>(out, kvm, kvd);
}